// Round 3
// baseline (1630.796 us; speedup 1.0000x reference)
//
#include <hip/hip_runtime.h>
#include <stdint.h>

#define B_DIM 8192
#define D_DIM 1024
#define H_DIM 2048
#define E_DIM 8
#define C_DIM 1024

typedef _Float16 f16x8 __attribute__((ext_vector_type(8)));
typedef float f32x4 __attribute__((ext_vector_type(4)));

__device__ __forceinline__ void store_val(float* p, float v) { *p = v; }
__device__ __forceinline__ void store_val(_Float16* p, float v) { *p = (_Float16)v; }

__device__ __forceinline__ void async_cp16(const void* g, void* l) {
  __builtin_amdgcn_global_load_lds((const __attribute__((address_space(1))) void*)g,
                                   (__attribute__((address_space(3))) void*)l, 16, 0, 0);
}

// ---------------------------------------------------------------------------
// 128x128 tile, BK=64, 4 waves (2x2, wave tile 64x64), double-buffered LDS
// (64 KiB total -> 2 blocks/CU: two independent barrier domains per CU so one
// block's MFMA region overlaps the other's LDS-read region).
// Per K-tile: 2 phases (kk=0,1), each {8 ds_read_b128; stage 4 gload_lds;
// barrier; lgkm0+sched_barrier; 16 MFMA; [kk1: vmcnt(0)]; barrier}.
// Stage safety (rigorous): A(t+1)->buf^1 issued after BAR2(t-1,kk1); every
// wave reached that barrier only after its MFMAs, which started only after
// lgkm0 drained its tile-(t-1) reads => all reads of buf^1 complete.
// L2 swizzle: blocks sharing an A row-panel (same by, all bx) map to the
// same XCD (by == xcd mod 8); requires gridDim.y % 8 == 0 (all grids comply).
// ---------------------------------------------------------------------------
template <bool RELU, bool BIAS, typename OUT_T, int K_CT>
__global__ void __launch_bounds__(256) gemm128(
    const _Float16* __restrict__ A, long aZ,
    const _Float16* __restrict__ Bt, long bZ,
    const float* __restrict__ bias, long biasZ,
    OUT_T* __restrict__ out, long outZ, long rs)
{
  constexpr int NT = K_CT / 64;
  __shared__ _Float16 ldsA[2 * 128 * 64];  // 32 KiB
  __shared__ _Float16 ldsB[2 * 128 * 64];  // 32 KiB

  const int z = blockIdx.z;
  A   += (size_t)z * aZ;
  Bt  += (size_t)z * bZ;
  if (BIAS) bias += (size_t)z * biasZ;
  out += (size_t)z * outZ;

  // A-panel-locality swizzle: slice-local linear index w -> xcd = w&7;
  // within an XCD walk bx fastest, then by in steps of 8.
  const int gx = gridDim.x;
  const int w  = blockIdx.y * gx + blockIdx.x;
  const int s  = w >> 3;
  const int bx = s % gx;
  const int by = (w & 7) + 8 * (s / gx);

  const int tid  = threadIdx.x;
  const int wave = tid >> 6;
  const int lane = tid & 63;
  const int q    = lane >> 4;
  const int l16  = lane & 15;
  const int l8   = lane >> 3;
  const int l7   = lane & 7;

  const int m0   = by * 128;
  const int n0   = bx * 128;
  const int wrow = (wave >> 1) * 64;
  const int wcol = (wave & 1) * 64;

  // Staging (verified layout): chunk ci = wave*4+i covers rows ci*8..ci*8+7;
  // pre-swizzled global source + linear LDS dest; slot j of row r holds
  // k-chunk j^(r&7).
  const int swz_st = ((l7 ^ l8) << 3);
  const _Float16* pa[4];
  const _Float16* pb[4];
#pragma unroll
  for (int i = 0; i < 4; ++i) {
    int ci = wave * 4 + i;
    pa[i] = A  + (size_t)(m0 + ci * 8 + l8) * K_CT + swz_st;
    pb[i] = Bt + (size_t)(n0 + ci * 8 + l8) * K_CT + swz_st;
  }

  // LDS read byte offsets (verified): row*128B + ((kchunk)^(row&7))*16B
  int a_off[2][4], b_off[2][4];
#pragma unroll
  for (int kk = 0; kk < 2; ++kk) {
#pragma unroll
    for (int r = 0; r < 4; ++r) {
      int sw = ((kk * 4 + q) ^ (l16 & 7)) << 4;
      a_off[kk][r] = (wrow + r * 16 + l16) * 128 + sw;
      b_off[kk][r] = (wcol + r * 16 + l16) * 128 + sw;
    }
  }

  f32x4 acc[4][4];
#pragma unroll
  for (int r = 0; r < 4; ++r)
#pragma unroll
    for (int c = 0; c < 4; ++c)
      acc[r][c] = (f32x4){0.f, 0.f, 0.f, 0.f};

  const char* lAc = (const char*)ldsA;
  const char* lBc = (const char*)ldsB;

  // Prologue: stage tile 0 into buf 0, full drain, barrier.
#pragma unroll
  for (int i = 0; i < 4; ++i) {
    int ci = wave * 4 + i;
    async_cp16(pa[i], ldsA + ci * 512);
    async_cp16(pb[i], ldsB + ci * 512);
    pa[i] += 64;  // -> tile t+1
    pb[i] += 64;
  }
  asm volatile("s_waitcnt vmcnt(0)" ::: "memory");
  __builtin_amdgcn_s_barrier();

  for (int t = 0; t < NT; ++t) {
    const int bofs = (t & 1) * 16384;         // byte offset, current buffer
    const int nbuf = ((t + 1) & 1) * 8192;    // elem offset, next buffer

    // ---- phase kk=0: reads + stage A(t+1) ----
    {
      f16x8 af[4], bfv[4];
#pragma unroll
      for (int r = 0; r < 4; ++r) af[r]  = *(const f16x8*)(lAc + bofs + a_off[0][r]);
#pragma unroll
      for (int c = 0; c < 4; ++c) bfv[c] = *(const f16x8*)(lBc + bofs + b_off[0][c]);
      if (t + 1 < NT) {
#pragma unroll
        for (int i = 0; i < 4; ++i)
          async_cp16(pa[i], ldsA + nbuf + (wave * 4 + i) * 512);
      }
      __builtin_amdgcn_s_barrier();
      asm volatile("s_waitcnt lgkmcnt(0)" ::: "memory");
      __builtin_amdgcn_sched_barrier(0);
      __builtin_amdgcn_s_setprio(1);
#pragma unroll
      for (int c = 0; c < 4; ++c)
#pragma unroll
        for (int r = 0; r < 4; ++r)
          acc[r][c] = __builtin_amdgcn_mfma_f32_16x16x32_f16(af[r], bfv[c], acc[r][c], 0, 0, 0);
      __builtin_amdgcn_s_setprio(0);
      __builtin_amdgcn_s_barrier();
    }

    // ---- phase kk=1: reads + stage B(t+1), end-of-tile vmcnt ----
    {
      f16x8 af[4], bfv[4];
#pragma unroll
      for (int r = 0; r < 4; ++r) af[r]  = *(const f16x8*)(lAc + bofs + a_off[1][r]);
#pragma unroll
      for (int c = 0; c < 4; ++c) bfv[c] = *(const f16x8*)(lBc + bofs + b_off[1][c]);
      if (t + 1 < NT) {
#pragma unroll
        for (int i = 0; i < 4; ++i)
          async_cp16(pb[i], ldsB + nbuf + (wave * 4 + i) * 512);
      }
      __builtin_amdgcn_s_barrier();
      asm volatile("s_waitcnt lgkmcnt(0)" ::: "memory");
      __builtin_amdgcn_sched_barrier(0);
      __builtin_amdgcn_s_setprio(1);
#pragma unroll
      for (int c = 0; c < 4; ++c)
#pragma unroll
        for (int r = 0; r < 4; ++r)
          acc[r][c] = __builtin_amdgcn_mfma_f32_16x16x32_f16(af[r], bfv[c], acc[r][c], 0, 0, 0);
      __builtin_amdgcn_s_setprio(0);
      // tile t+1 must be fully in LDS before anyone enters tile t+1
      asm volatile("s_waitcnt vmcnt(0)" ::: "memory");
      __builtin_amdgcn_s_barrier();
#pragma unroll
      for (int i = 0; i < 4; ++i) { pa[i] += 64; pb[i] += 64; }
    }
  }

  // Epilogue (verified): D[row=q*4+i][col=l16] per 16x16 tile.
#pragma unroll
  for (int c = 0; c < 4; ++c) {
    int col = n0 + wcol + c * 16 + l16;
    float bv = BIAS ? bias[col] : 0.f;
#pragma unroll
    for (int r = 0; r < 4; ++r) {
      int row = m0 + wrow + r * 16 + q * 4;
      f32x4 v = acc[r][c];
#pragma unroll
      for (int i = 0; i < 4; ++i) {
        float xv = v[i] + bv;
        if (RELU) xv = fmaxf(xv, 0.f);
        store_val(out + (size_t)(row + i) * rs + col, xv);
      }
    }
  }
}

// ---------------------------------------------------------------------------
__global__ void cast_f32_f16(const float* __restrict__ in, _Float16* __restrict__ out, int n) {
  int i = (blockIdx.x * blockDim.x + threadIdx.x) * 4;
  if (i >= n) return;
  float4 v = *(const float4*)(in + i);
  union { _Float16 h[4]; uint2 u; } r;
  r.h[0] = (_Float16)v.x; r.h[1] = (_Float16)v.y;
  r.h[2] = (_Float16)v.z; r.h[3] = (_Float16)v.w;
  *(uint2*)(out + i) = r.u;
}

// in [R][Cn] fp32 (batched over z) -> out [Cn][R] fp16
__global__ void transpose_cast(const float* __restrict__ in, _Float16* __restrict__ out,
                               int R, int Cn) {
  __shared__ float tile[32][33];
  in  += (size_t)blockIdx.z * R * Cn;
  out += (size_t)blockIdx.z * R * Cn;
  int c0 = blockIdx.x * 32, r0 = blockIdx.y * 32;
  int tx = threadIdx.x, ty = threadIdx.y;
#pragma unroll
  for (int i = ty; i < 32; i += 8)
    tile[i][tx] = in[(size_t)(r0 + i) * Cn + c0 + tx];
  __syncthreads();
#pragma unroll
  for (int i = ty; i < 32; i += 8)
    out[(size_t)(c0 + i) * R + r0 + tx] = (_Float16)tile[tx][i];
}

// scores = softmax(g[B][D](f16) @ w2[D][8] + b2), one block per row.
// Vectorized g loads: 32 slices x f16x8, 8 expert-groups.
__global__ void gate2_softmax(const _Float16* __restrict__ g, const float* __restrict__ w2,
                              const float* __restrict__ b2, float* __restrict__ scores) {
  int b = blockIdx.x;
  int t = threadIdx.x;             // 256
  int e = t >> 5, slice = t & 31;  // 8 experts x 32 slices
  const _Float16* gr = g + (size_t)b * D_DIM;
  float acc = 0.f;
  for (int d0 = slice * 8; d0 < D_DIM; d0 += 256) {
    f16x8 gv = *(const f16x8*)(gr + d0);
#pragma unroll
    for (int j = 0; j < 8; ++j)
      acc += (float)gv[j] * w2[(d0 + j) * 8 + e];
  }
  __shared__ float red[256];
  red[t] = acc;
  __syncthreads();
  for (int ss = 16; ss > 0; ss >>= 1) {
    if (slice < ss) red[t] += red[t + ss];
    __syncthreads();
  }
  __shared__ float sm[8];
  if (slice == 0) sm[e] = red[t] + b2[e];
  __syncthreads();
  if (t == 0) {
    float mx = sm[0];
#pragma unroll
    for (int i = 1; i < 8; ++i) mx = fmaxf(mx, sm[i]);
    float ex[8], sum = 0.f;
#pragma unroll
    for (int i = 0; i < 8; ++i) { ex[i] = expf(sm[i] - mx); sum += ex[i]; }
    float inv = 1.f / sum;
#pragma unroll
    for (int i = 0; i < 8; ++i) scores[(size_t)b * 8 + i] = ex[i] * inv;
  }
}

// bc[e][c] = cb[c] + sum_k b2[e][k] * cw[k][c]   (combined classifier bias)
__global__ void combined_bias(const float* __restrict__ b2, const float* __restrict__ cw,
                              const float* __restrict__ cb, float* __restrict__ bc) {
  int e  = blockIdx.y;
  int cl = threadIdx.x & 63;
  int c  = blockIdx.x * 64 + cl;
  int ks = threadIdx.x >> 6;  // 4 k-slices
  float acc = 0.f;
  for (int k = ks; k < H_DIM; k += 4)
    acc += b2[e * H_DIM + k] * cw[(size_t)k * C_DIM + c];
  __shared__ float red[256];
  red[threadIdx.x] = acc;
  __syncthreads();
  if (ks == 0)
    bc[(size_t)e * C_DIM + c] = red[cl] + red[cl + 64] + red[cl + 128] + red[cl + 192] + cb[c];
}

// ---------------------------------------------------------------------------
extern "C" void kernel_launch(void* const* d_in, const int* in_sizes, int n_in,
                              void* d_out, int out_size, void* d_ws, size_t ws_size,
                              hipStream_t stream) {
  const float* x   = (const float*)d_in[0];
  const float* gw1 = (const float*)d_in[1];
  const float* gb1 = (const float*)d_in[2];
  const float* gw2 = (const float*)d_in[3];
  const float* gb2 = (const float*)d_in[4];
  const float* W1  = (const float*)d_in[5];
  const float* b1  = (const float*)d_in[6];
  const float* W2  = (const float*)d_in[7];
  const float* b2  = (const float*)d_in[8];
  const float* cw  = (const float*)d_in[9];
  const float* cb  = (const float*)d_in[10];

  char* ws = (char*)d_ws;
  _Float16* xb     = (_Float16*)(ws);                    // B*D        16 MB
  _Float16* g      = (_Float16*)(ws + 16777216ull);      // B*D        16 MB
  _Float16* gw1t   = (_Float16*)(ws + 33554432ull);      // D*D         2 MB
  _Float16* W1t    = (_Float16*)(ws + 35651584ull);      // E*H*D      32 MB
  _Float16* W2c    = (_Float16*)(ws + 69206016ull);      // E*H*H      64 MB (cast, NOT transposed)
  _Float16* cwt    = (_Float16*)(ws + 136314880ull);     // C*H         4 MB
  _Float16* WcombT = (_Float16*)(ws + 140509184ull);     // E*C*H      32 MB
  float*    bc     = (float*)   (ws + 174063616ull);     // E*C        32 KB
  _Float16* h_all  = (_Float16*)(ws + 174096384ull);     // E*B*H     256 MB
                                                         // total ~422 MB

  float* logits = (float*)d_out;
  float* scores = logits + (size_t)B_DIM * E_DIM * C_DIM;

  // Precision prep: casts + [N][K] weight transposes
  cast_f32_f16<<<B_DIM * D_DIM / 4 / 256, 256, 0, stream>>>(x, xb, B_DIM * D_DIM);
  transpose_cast<<<dim3(32, 32, 1), dim3(32, 8), 0, stream>>>(gw1, gw1t, D_DIM, D_DIM);
  transpose_cast<<<dim3(64, 32, 8), dim3(32, 8), 0, stream>>>(W1, W1t, D_DIM, H_DIM);
  cast_f32_f16<<<E_DIM * H_DIM * H_DIM / 4 / 256, 256, 0, stream>>>(W2, W2c, E_DIM * H_DIM * H_DIM);
  transpose_cast<<<dim3(32, 64, 1), dim3(32, 8), 0, stream>>>(cw, cwt, H_DIM, C_DIM);

  // Router: g = relu(xb @ gw1 + gb1)   M=8192, N=1024, K=1024
  gemm128<true, true, _Float16, D_DIM><<<dim3(8, 64, 1), 256, 0, stream>>>(
      xb, 0, gw1t, 0, gb1, 0, g, 0, (long)D_DIM);
  gate2_softmax<<<B_DIM, 256, 0, stream>>>(g, gw2, gb2, scores);

  // Classifier folding: WcombT[e][c][h'] = sum_k2 Wc[k2][c] * W2[e][h'][k2]
  //   M=C=1024, N=H=2048, K=H=2048 -> grid (16, 8, 8)
  gemm128<false, false, _Float16, H_DIM><<<dim3(16, 8, 8), 256, 0, stream>>>(
      cwt, 0, W2c, (long)H_DIM * H_DIM, nullptr, 0,
      WcombT, (long)C_DIM * H_DIM, (long)H_DIM);
  combined_bias<<<dim3(C_DIM / 64, E_DIM), 256, 0, stream>>>(b2, cw, cb, bc);

  // Layer 1, all experts batched: h_all[e] = relu(x @ W1[e] + b1[e])
  gemm128<true, true, _Float16, D_DIM><<<dim3(16, 64, 8), 256, 0, stream>>>(
      xb, 0, W1t, (long)H_DIM * D_DIM, b1, (long)H_DIM,
      h_all, (long)B_DIM * H_DIM, (long)H_DIM);

  // Fused layer2+classifier: logits[:,e,:] = h_all[e] @ Wcomb[e] + bc[e]
  gemm128<false, true, float, H_DIM><<<dim3(8, 64, 8), 256, 0, stream>>>(
      h_all, (long)B_DIM * H_DIM, WcombT, (long)C_DIM * H_DIM, bc, (long)C_DIM,
      logits, (long)C_DIM, (long)(E_DIM * C_DIM));
}

// Round 4
// 1468.904 us; speedup vs baseline: 1.1102x; 1.1102x over previous
//
#include <hip/hip_runtime.h>
#include <stdint.h>

#define B_DIM 8192
#define D_DIM 1024
#define H_DIM 2048
#define E_DIM 8
#define C_DIM 1024

typedef _Float16 f16x8 __attribute__((ext_vector_type(8)));
typedef float f32x4 __attribute__((ext_vector_type(4)));

__device__ __forceinline__ void store_val(float* p, float v) { *p = v; }
__device__ __forceinline__ void store_val(_Float16* p, float v) { *p = (_Float16)v; }

__device__ __forceinline__ void async_cp16(const void* g, void* l) {
  __builtin_amdgcn_global_load_lds((const __attribute__((address_space(1))) void*)g,
                                   (__attribute__((address_space(3))) void*)l, 16, 0, 0);
}

// ---------------------------------------------------------------------------
// 128x128 tile kernel (m97 structure) — kept for the router GEMM only.
// ---------------------------------------------------------------------------
template <bool RELU, bool BIAS, typename OUT_T>
__global__ void __launch_bounds__(256) gemm_bt(
    const _Float16* __restrict__ A, long aZ,
    const _Float16* __restrict__ Bt, long bZ,
    const float* __restrict__ bias, long biasZ,
    OUT_T* __restrict__ out, long outZ,
    int K, long rs)
{
  __shared__ _Float16 ldsA[128 * 64];
  __shared__ _Float16 ldsB[128 * 64];

  const int z = blockIdx.z;
  A   += (size_t)z * aZ;
  Bt  += (size_t)z * bZ;
  if (BIAS) bias += (size_t)z * biasZ;
  out += (size_t)z * outZ;

  const int tid  = threadIdx.x;
  const int wave = tid >> 6;
  const int lane = tid & 63;
  const int q    = lane >> 4;
  const int l16  = lane & 15;
  const int l8   = lane >> 3;
  const int l7   = lane & 7;

  const int m0   = blockIdx.y * 128;
  const int n0   = blockIdx.x * 128;
  const int wrow = (wave >> 1) * 64;
  const int wcol = (wave & 1) * 64;

  const int swz_st = ((l7 ^ l8) << 3);
  const _Float16* pa[4];
  const _Float16* pb[4];
#pragma unroll
  for (int i = 0; i < 4; ++i) {
    int ci = wave * 4 + i;
    pa[i] = A  + (size_t)(m0 + ci * 8 + l8) * K + swz_st;
    pb[i] = Bt + (size_t)(n0 + ci * 8 + l8) * K + swz_st;
  }

  int a_off[2][4], b_off[2][4];
#pragma unroll
  for (int kk = 0; kk < 2; ++kk) {
#pragma unroll
    for (int r = 0; r < 4; ++r) {
      int sw = ((kk * 4 + q) ^ (l16 & 7)) << 4;
      a_off[kk][r] = (wrow + r * 16 + l16) * 128 + sw;
      b_off[kk][r] = (wcol + r * 16 + l16) * 128 + sw;
    }
  }

  f32x4 acc[4][4];
#pragma unroll
  for (int r = 0; r < 4; ++r)
#pragma unroll
    for (int c = 0; c < 4; ++c)
      acc[r][c] = (f32x4){0.f, 0.f, 0.f, 0.f};

  const char* lAc = (const char*)ldsA;
  const char* lBc = (const char*)ldsB;

  for (int kt = 0; kt < K; kt += 64) {
    __syncthreads();
#pragma unroll
    for (int i = 0; i < 4; ++i) {
      int ci = wave * 4 + i;
      async_cp16(pa[i], ldsA + ci * 512);
      async_cp16(pb[i], ldsB + ci * 512);
      pa[i] += 64;
      pb[i] += 64;
    }
    __syncthreads();
#pragma unroll
    for (int kk = 0; kk < 2; ++kk) {
      f16x8 af[4], bfv[4];
#pragma unroll
      for (int r = 0; r < 4; ++r) af[r]  = *(const f16x8*)(lAc + a_off[kk][r]);
#pragma unroll
      for (int c = 0; c < 4; ++c) bfv[c] = *(const f16x8*)(lBc + b_off[kk][c]);
#pragma unroll
      for (int r = 0; r < 4; ++r)
#pragma unroll
        for (int c = 0; c < 4; ++c)
          acc[r][c] = __builtin_amdgcn_mfma_f32_16x16x32_f16(af[r], bfv[c], acc[r][c], 0, 0, 0);
    }
  }

#pragma unroll
  for (int c = 0; c < 4; ++c) {
    int col = n0 + wcol + c * 16 + l16;
    float bv = BIAS ? bias[col] : 0.f;
#pragma unroll
    for (int r = 0; r < 4; ++r) {
      int row = m0 + wrow + r * 16 + q * 4;
      f32x4 v = acc[r][c];
#pragma unroll
      for (int i = 0; i < 4; ++i) {
        float xv = v[i] + bv;
        if (RELU) xv = fmaxf(xv, 0.f);
        store_val(out + (size_t)(row + i) * rs + col, xv);
      }
    }
  }
}

// ---------------------------------------------------------------------------
// 256x256 tile, BK=64, 8 waves (2Mx4N), kk-split 4-phase K-loop, one barrier
// per phase, counted vmcnt, templated K.
// R4 change: NO per-phase lgkmcnt(0)/sched_barrier drain — the compiler emits
// counted lgkmcnt between each ds_read and its consuming MFMA, so LDS service
// overlaps the MFMA burst instead of serializing with it.
// Stage safety: a phase's reads complete before its MFMAs issue (HW counted
// waits); MFMAs precede the wave's barrier; so when all waves cross barrier
// (p-1), all phase-(p-1) reads are complete, and any stage issued in phase p
// (after that barrier) targets only cells last read at phase <= p-1.
//   p0: stage A(t+1).lo -> buf^1 (A buf^1 last read in tile t-1)
//   p1: stage A(t+1).hi -> buf^1
//   p3: stage B(t+2)    -> buf   (B(t) last read at p2)
// vmcnt(4) at p3: drains A(t+1)+B(t+1) (needed next tile), keeps B(t+2)'s 4
// loads in flight across the barrier. vmcnt(0) only for the last 2 tiles.
// ---------------------------------------------------------------------------
template <bool RELU, bool BIAS, typename OUT_T, int K_CT>
__global__ void __launch_bounds__(512) gemm256(
    const _Float16* __restrict__ A, long aZ,
    const _Float16* __restrict__ Bt, long bZ,
    const float* __restrict__ bias, long biasZ,
    OUT_T* __restrict__ out, long outZ, long rs)
{
  constexpr int NT = K_CT / 64;
  __shared__ _Float16 ldsA[2 * 256 * 64];
  __shared__ _Float16 ldsB[2 * 256 * 64];

  const int z = blockIdx.z;
  A   += (size_t)z * aZ;
  Bt  += (size_t)z * bZ;
  if (BIAS) bias += (size_t)z * biasZ;
  out += (size_t)z * outZ;

  // T1: bijective XCD swizzle of (x,y); all grids here have nwg % 8 == 0.
  const int nwg = gridDim.x * gridDim.y;
  const int wg  = blockIdx.y * gridDim.x + blockIdx.x;
  const int sw  = (wg & 7) * (nwg >> 3) + (wg >> 3);
  const int bx  = sw % gridDim.x;
  const int by  = sw / gridDim.x;

  const int tid  = threadIdx.x;
  const int wave = tid >> 6;
  const int lane = tid & 63;
  const int q    = lane >> 4;
  const int l16  = lane & 15;
  const int l8   = lane >> 3;
  const int l7   = lane & 7;

  const int m0   = by * 256;
  const int n0   = bx * 256;
  const int wm   = wave >> 2;   // 0..1 -> 128-row slab of A-tile
  const int wn   = wave & 3;    // 0..3 -> 64-col slab of B-tile
  const int wrow = wm * 128;
  const int wcol = wn * 64;

  // Pre-swizzled global source + linear LDS dest; slot j of row r holds
  // k-chunk j^(r&7).
  const int swz_st = ((l7 ^ l8) << 3);
  const _Float16* paB = A  + (size_t)(m0 + wave * 16 + l8) * K_CT + swz_st;
  const _Float16* pbB = Bt + (size_t)(n0 + wave * 16 + l8) * K_CT + swz_st;

  int a_base[2], b_base[2];
#pragma unroll
  for (int kk = 0; kk < 2; ++kk) {
    int swr = (((kk * 4 + q) ^ (l16 & 7)) << 4);
    a_base[kk] = (wrow + l16) * 128 + swr;
    b_base[kk] = (wcol + l16) * 128 + swr;
  }

  f32x4 acc[8][4];
#pragma unroll
  for (int r = 0; r < 8; ++r)
#pragma unroll
    for (int c = 0; c < 4; ++c)
      acc[r][c] = (f32x4){0.f, 0.f, 0.f, 0.f};

  const char* lA = (const char*)ldsA;
  const char* lB = (const char*)ldsB;

  // bufe = element offset of target buffer (0 / 16384); hh = 128-row half.
#define STAGE_A(bufe, hh, ptr)                                                        \
  {                                                                                   \
    _Pragma("unroll")                                                                 \
    for (int i_ = 0; i_ < 2; ++i_)                                                    \
      async_cp16((ptr) + (size_t)((hh) * 128 + i_ * 8) * K_CT,                        \
                 (void*)(ldsA + (bufe) + (hh) * 8192 + (wave * 2 + i_) * 512));       \
  }
#define STAGE_B(bufe, hh, ptr)                                                        \
  {                                                                                   \
    _Pragma("unroll")                                                                 \
    for (int i_ = 0; i_ < 2; ++i_)                                                    \
      async_cp16((ptr) + (size_t)((hh) * 128 + i_ * 8) * K_CT,                        \
                 (void*)(ldsB + (bufe) + (hh) * 8192 + (wave * 2 + i_) * 512));       \
  }

  // Prologue: tile0 A+B, tile1 B (12 loads); vmcnt(4) keeps tile1-B in flight.
  STAGE_A(0, 0, paB) STAGE_A(0, 1, paB)
  STAGE_B(0, 0, pbB) STAGE_B(0, 1, pbB)
  STAGE_B(16384, 0, pbB + 64) STAGE_B(16384, 1, pbB + 64)
  asm volatile("s_waitcnt vmcnt(4)" ::: "memory");
  __builtin_amdgcn_s_barrier();

  const _Float16* pa_t = paB + 64;   // -> tile t+1
  const _Float16* pb_t = pbB + 128;  // -> tile t+2

  for (int t = 0; t < NT; ++t) {
    const int bofs  = (t & 1) * 32768;        // byte offset, current buffer
    const int nbufe = ((t + 1) & 1) * 16384;  // elem offset, A target buffer
    const int cbufe = (t & 1) * 16384;        // elem offset, B(t+2) target
    f16x8 bf[4];
#pragma unroll
    for (int p = 0; p < 4; ++p) {
      const int kk = p >> 1, h = p & 1;
      if (h == 0) {
#pragma unroll
        for (int c = 0; c < 4; ++c)
          bf[c] = *(const f16x8*)(lB + bofs + b_base[kk] + c * 2048);
      }
      f16x8 af[4];
#pragma unroll
      for (int r = 0; r < 4; ++r)
        af[r] = *(const f16x8*)(lA + bofs + a_base[kk] + (h * 4 + r) * 2048);

      if (p == 0 && t + 1 < NT) STAGE_A(nbufe, 0, pa_t)
      if (p == 1 && t + 1 < NT) STAGE_A(nbufe, 1, pa_t)
      if (p == 3 && t + 2 < NT) { STAGE_B(cbufe, 0, pb_t) STAGE_B(cbufe, 1, pb_t) }

      __builtin_amdgcn_s_setprio(1);
#pragma unroll
      for (int c = 0; c < 4; ++c)
#pragma unroll
        for (int r = 0; r < 4; ++r)
          acc[h * 4 + r][c] = __builtin_amdgcn_mfma_f32_16x16x32_f16(
              af[r], bf[c], acc[h * 4 + r][c], 0, 0, 0);
      __builtin_amdgcn_s_setprio(0);

      if (p == 3) {
        if (t < NT - 2) asm volatile("s_waitcnt vmcnt(4)" ::: "memory");
        else            asm volatile("s_waitcnt vmcnt(0)" ::: "memory");
      }
      __builtin_amdgcn_s_barrier();
    }
    pa_t += 64;
    pb_t += 64;
  }
#undef STAGE_A
#undef STAGE_B

  // Epilogue: D[row=q*4+i][col=l16] per 16x16 frag (verified C/D layout).
#pragma unroll
  for (int c = 0; c < 4; ++c) {
    int col = n0 + wcol + c * 16 + l16;
    float bv = BIAS ? bias[col] : 0.f;
#pragma unroll
    for (int r = 0; r < 8; ++r) {
      int row = m0 + wrow + r * 16 + q * 4;
      f32x4 v = acc[r][c];
#pragma unroll
      for (int i = 0; i < 4; ++i) {
        float xv = v[i] + bv;
        if (RELU) xv = fmaxf(xv, 0.f);
        store_val(out + (size_t)(row + i) * rs + col, xv);
      }
    }
  }
}

// ---------------------------------------------------------------------------
__global__ void cast_f32_f16(const float* __restrict__ in, _Float16* __restrict__ out, int n) {
  int i = (blockIdx.x * blockDim.x + threadIdx.x) * 4;
  if (i >= n) return;
  float4 v = *(const float4*)(in + i);
  union { _Float16 h[4]; uint2 u; } r;
  r.h[0] = (_Float16)v.x; r.h[1] = (_Float16)v.y;
  r.h[2] = (_Float16)v.z; r.h[3] = (_Float16)v.w;
  *(uint2*)(out + i) = r.u;
}

// in [R][Cn] fp32 (batched over z) -> out [Cn][R] fp16
__global__ void transpose_cast(const float* __restrict__ in, _Float16* __restrict__ out,
                               int R, int Cn) {
  __shared__ float tile[32][33];
  in  += (size_t)blockIdx.z * R * Cn;
  out += (size_t)blockIdx.z * R * Cn;
  int c0 = blockIdx.x * 32, r0 = blockIdx.y * 32;
  int tx = threadIdx.x, ty = threadIdx.y;
#pragma unroll
  for (int i = ty; i < 32; i += 8)
    tile[i][tx] = in[(size_t)(r0 + i) * Cn + c0 + tx];
  __syncthreads();
#pragma unroll
  for (int i = ty; i < 32; i += 8)
    out[(size_t)(c0 + i) * R + r0 + tx] = (_Float16)tile[tx][i];
}

// scores = softmax(g[B][D](f16) @ w2[D][8] + b2), one block per row.
// Vectorized g loads: 32 slices x f16x8, 8 expert-groups.
__global__ void gate2_softmax(const _Float16* __restrict__ g, const float* __restrict__ w2,
                              const float* __restrict__ b2, float* __restrict__ scores) {
  int b = blockIdx.x;
  int t = threadIdx.x;             // 256
  int e = t >> 5, slice = t & 31;  // 8 experts x 32 slices
  const _Float16* gr = g + (size_t)b * D_DIM;
  float acc = 0.f;
  for (int d0 = slice * 8; d0 < D_DIM; d0 += 256) {
    f16x8 gv = *(const f16x8*)(gr + d0);
#pragma unroll
    for (int j = 0; j < 8; ++j)
      acc += (float)gv[j] * w2[(d0 + j) * 8 + e];
  }
  __shared__ float red[256];
  red[t] = acc;
  __syncthreads();
  for (int ss = 16; ss > 0; ss >>= 1) {
    if (slice < ss) red[t] += red[t + ss];
    __syncthreads();
  }
  __shared__ float sm[8];
  if (slice == 0) sm[e] = red[t] + b2[e];
  __syncthreads();
  if (t == 0) {
    float mx = sm[0];
#pragma unroll
    for (int i = 1; i < 8; ++i) mx = fmaxf(mx, sm[i]);
    float ex[8], sum = 0.f;
#pragma unroll
    for (int i = 0; i < 8; ++i) { ex[i] = expf(sm[i] - mx); sum += ex[i]; }
    float inv = 1.f / sum;
#pragma unroll
    for (int i = 0; i < 8; ++i) scores[(size_t)b * 8 + i] = ex[i] * inv;
  }
}

// bc[e][c] = cb[c] + sum_k b2[e][k] * cw[k][c]   (combined classifier bias)
__global__ void combined_bias(const float* __restrict__ b2, const float* __restrict__ cw,
                              const float* __restrict__ cb, float* __restrict__ bc) {
  int e  = blockIdx.y;
  int cl = threadIdx.x & 63;
  int c  = blockIdx.x * 64 + cl;
  int ks = threadIdx.x >> 6;  // 4 k-slices
  float acc = 0.f;
  for (int k = ks; k < H_DIM; k += 4)
    acc += b2[e * H_DIM + k] * cw[(size_t)k * C_DIM + c];
  __shared__ float red[256];
  red[threadIdx.x] = acc;
  __syncthreads();
  if (ks == 0)
    bc[(size_t)e * C_DIM + c] = red[cl] + red[cl + 64] + red[cl + 128] + red[cl + 192] + cb[c];
}

// ---------------------------------------------------------------------------
extern "C" void kernel_launch(void* const* d_in, const int* in_sizes, int n_in,
                              void* d_out, int out_size, void* d_ws, size_t ws_size,
                              hipStream_t stream) {
  const float* x   = (const float*)d_in[0];
  const float* gw1 = (const float*)d_in[1];
  const float* gb1 = (const float*)d_in[2];
  const float* gw2 = (const float*)d_in[3];
  const float* gb2 = (const float*)d_in[4];
  const float* W1  = (const float*)d_in[5];
  const float* b1  = (const float*)d_in[6];
  const float* W2  = (const float*)d_in[7];
  const float* b2  = (const float*)d_in[8];
  const float* cw  = (const float*)d_in[9];
  const float* cb  = (const float*)d_in[10];

  char* ws = (char*)d_ws;
  _Float16* xb     = (_Float16*)(ws);                    // B*D        16 MB
  _Float16* g      = (_Float16*)(ws + 16777216ull);      // B*D        16 MB
  _Float16* gw1t   = (_Float16*)(ws + 33554432ull);      // D*D         2 MB
  _Float16* W1t    = (_Float16*)(ws + 35651584ull);      // E*H*D      32 MB
  _Float16* W2c    = (_Float16*)(ws + 69206016ull);      // E*H*H      64 MB (cast, NOT transposed)
  _Float16* cwt    = (_Float16*)(ws + 136314880ull);     // C*H         4 MB
  _Float16* WcombT = (_Float16*)(ws + 140509184ull);     // E*C*H      32 MB
  float*    bc     = (float*)   (ws + 174063616ull);     // E*C        32 KB
  _Float16* h_all  = (_Float16*)(ws + 174096384ull);     // E*B*H     256 MB
                                                         // total ~422 MB

  float* logits = (float*)d_out;
  float* scores = logits + (size_t)B_DIM * E_DIM * C_DIM;

  // Precision prep: casts + [N][K] weight transposes
  cast_f32_f16<<<B_DIM * D_DIM / 4 / 256, 256, 0, stream>>>(x, xb, B_DIM * D_DIM);
  transpose_cast<<<dim3(32, 32, 1), dim3(32, 8), 0, stream>>>(gw1, gw1t, D_DIM, D_DIM);
  transpose_cast<<<dim3(64, 32, 8), dim3(32, 8), 0, stream>>>(W1, W1t, D_DIM, H_DIM);
  cast_f32_f16<<<E_DIM * H_DIM * H_DIM / 4 / 256, 256, 0, stream>>>(W2, W2c, E_DIM * H_DIM * H_DIM);
  transpose_cast<<<dim3(32, 64, 1), dim3(32, 8), 0, stream>>>(cw, cwt, H_DIM, C_DIM);

  // Router (128^2 kernel)
  gemm_bt<true, true, _Float16><<<dim3(8, 64, 1), 256, 0, stream>>>(
      xb, 0, gw1t, 0, gb1, 0, g, 0, D_DIM, (long)D_DIM);
  gate2_softmax<<<B_DIM, 256, 0, stream>>>(g, gw2, gb2, scores);

  // Classifier folding: WcombT[e][c][h'] = sum_k2 Wc[k2][c] * W2[e][h'][k2]
  //   M=C=1024, N=H=2048, K=H=2048 -> grid (8,4,8) = 256 blocks, 1/CU.
  gemm256<false, false, _Float16, H_DIM><<<dim3(8, 4, 8), 512, 0, stream>>>(
      cwt, 0, W2c, (long)H_DIM * H_DIM, nullptr, 0,
      WcombT, (long)C_DIM * H_DIM, (long)H_DIM);
  combined_bias<<<dim3(C_DIM / 64, E_DIM), 256, 0, stream>>>(b2, cw, cb, bc);

  // Layer 1, all experts batched: h_all[e] = relu(x @ W1[e] + b1[e])
  gemm256<true, true, _Float16, D_DIM><<<dim3(8, 32, 8), 512, 0, stream>>>(
      xb, 0, W1t, (long)H_DIM * D_DIM, b1, (long)H_DIM,
      h_all, (long)B_DIM * H_DIM, (long)H_DIM);

  // Fused layer2+classifier: logits[:,e,:] = h_all[e] @ Wcomb[e] + bc[e]
  gemm256<false, true, float, H_DIM><<<dim3(4, 32, 8), 512, 0, stream>>>(
      h_all, (long)B_DIM * H_DIM, WcombT, (long)C_DIM * H_DIM, bc, (long)C_DIM,
      logits, (long)C_DIM, (long)(E_DIM * C_DIM));
}

// Round 5
// 1443.246 us; speedup vs baseline: 1.1299x; 1.0178x over previous
//
#include <hip/hip_runtime.h>
#include <stdint.h>

#define B_DIM 8192
#define D_DIM 1024
#define H_DIM 2048
#define E_DIM 8
#define C_DIM 1024

typedef _Float16 f16x8 __attribute__((ext_vector_type(8)));
typedef float f32x4 __attribute__((ext_vector_type(4)));

__device__ __forceinline__ void store_val(float* p, float v) { *p = v; }
__device__ __forceinline__ void store_val(_Float16* p, float v) { *p = (_Float16)v; }

__device__ __forceinline__ void async_cp16(const void* g, void* l) {
  __builtin_amdgcn_global_load_lds((const __attribute__((address_space(1))) void*)g,
                                   (__attribute__((address_space(3))) void*)l, 16, 0, 0);
}

// ---------------------------------------------------------------------------
// 128x128 tile kernel (m97 structure) — router GEMM only.
// ---------------------------------------------------------------------------
template <bool RELU, bool BIAS, typename OUT_T>
__global__ void __launch_bounds__(256) gemm_bt(
    const _Float16* __restrict__ A, long aZ,
    const _Float16* __restrict__ Bt, long bZ,
    const float* __restrict__ bias, long biasZ,
    OUT_T* __restrict__ out, long outZ,
    int K, long rs)
{
  __shared__ _Float16 ldsA[128 * 64];
  __shared__ _Float16 ldsB[128 * 64];

  const int z = blockIdx.z;
  A   += (size_t)z * aZ;
  Bt  += (size_t)z * bZ;
  if (BIAS) bias += (size_t)z * biasZ;
  out += (size_t)z * outZ;

  const int tid  = threadIdx.x;
  const int wave = tid >> 6;
  const int lane = tid & 63;
  const int q    = lane >> 4;
  const int l16  = lane & 15;
  const int l8   = lane >> 3;
  const int l7   = lane & 7;

  const int m0   = blockIdx.y * 128;
  const int n0   = blockIdx.x * 128;
  const int wrow = (wave >> 1) * 64;
  const int wcol = (wave & 1) * 64;

  const int swz_st = ((l7 ^ l8) << 3);
  const _Float16* pa[4];
  const _Float16* pb[4];
#pragma unroll
  for (int i = 0; i < 4; ++i) {
    int ci = wave * 4 + i;
    pa[i] = A  + (size_t)(m0 + ci * 8 + l8) * K + swz_st;
    pb[i] = Bt + (size_t)(n0 + ci * 8 + l8) * K + swz_st;
  }

  int a_off[2][4], b_off[2][4];
#pragma unroll
  for (int kk = 0; kk < 2; ++kk) {
#pragma unroll
    for (int r = 0; r < 4; ++r) {
      int sw = ((kk * 4 + q) ^ (l16 & 7)) << 4;
      a_off[kk][r] = (wrow + r * 16 + l16) * 128 + sw;
      b_off[kk][r] = (wcol + r * 16 + l16) * 128 + sw;
    }
  }

  f32x4 acc[4][4];
#pragma unroll
  for (int r = 0; r < 4; ++r)
#pragma unroll
    for (int c = 0; c < 4; ++c)
      acc[r][c] = (f32x4){0.f, 0.f, 0.f, 0.f};

  const char* lAc = (const char*)ldsA;
  const char* lBc = (const char*)ldsB;

  for (int kt = 0; kt < K; kt += 64) {
    __syncthreads();
#pragma unroll
    for (int i = 0; i < 4; ++i) {
      int ci = wave * 4 + i;
      async_cp16(pa[i], ldsA + ci * 512);
      async_cp16(pb[i], ldsB + ci * 512);
      pa[i] += 64;
      pb[i] += 64;
    }
    __syncthreads();
#pragma unroll
    for (int kk = 0; kk < 2; ++kk) {
      f16x8 af[4], bfv[4];
#pragma unroll
      for (int r = 0; r < 4; ++r) af[r]  = *(const f16x8*)(lAc + a_off[kk][r]);
#pragma unroll
      for (int c = 0; c < 4; ++c) bfv[c] = *(const f16x8*)(lBc + b_off[kk][c]);
#pragma unroll
      for (int r = 0; r < 4; ++r)
#pragma unroll
        for (int c = 0; c < 4; ++c)
          acc[r][c] = __builtin_amdgcn_mfma_f32_16x16x32_f16(af[r], bfv[c], acc[r][c], 0, 0, 0);
    }
  }

#pragma unroll
  for (int c = 0; c < 4; ++c) {
    int col = n0 + wcol + c * 16 + l16;
    float bv = BIAS ? bias[col] : 0.f;
#pragma unroll
    for (int r = 0; r < 4; ++r) {
      int row = m0 + wrow + r * 16 + q * 4;
      f32x4 v = acc[r][c];
#pragma unroll
      for (int i = 0; i < 4; ++i) {
        float xv = v[i] + bv;
        if (RELU) xv = fmaxf(xv, 0.f);
        store_val(out + (size_t)(row + i) * rs + col, xv);
      }
    }
  }
}

// ---------------------------------------------------------------------------
// 256x256 tile, BK=64, 8 waves (2Mx4N), 4 phases/K-tile with REGISTER
// double-buffering: phase p issues ds_reads for MFMA set p+1, then runs set
// p's MFMAs on registers loaded LAST phase. MFMAs never wait on same-phase
// reads -> LDS pipe drains under the MFMA burst (counted lgkm, compiler-
// emitted). Sets: S0=(kk0,rows0-3) S1=(kk1,rows0-3) S2=(kk0,rows4-7)
// S3=(kk1,rows4-7); bf0(kk0)/bf1(kk1) held per-tile, afA/afB ping-pong.
//   P0: read afB=S1.A, bf1      (8) | stage A(t+1) (4) | MFMA S0 | bar
//   P1: read afA=S2.A           (4) | stage B(t+1) (4) | MFMA S1 | bar
//   P2: read afB=S3.A           (4) |                  | MFMA S2 | vmcnt(0)
//       (free: t+1 issued >=1.5 phases ago) | bar  -> publishes t+1
//   P3: read afA=S0'.A, bf0' from buf^1 (t+1)  (8) | MFMA S3 | bar
// Stage safety: A(t+1)->buf^1 at P0(t): buf^1 A last read at P2(t-1),
// consumed by P3(t-1) MFMAs before the P3 barrier all waves crossed.
// B(t+1)->buf^1 at P1(t): buf^1 B last read at P0(t-1)'s bf load. Both safe.
// ---------------------------------------------------------------------------
template <bool RELU, bool BIAS, typename OUT_T, int K_CT>
__global__ void __launch_bounds__(512) gemm256(
    const _Float16* __restrict__ A, long aZ,
    const _Float16* __restrict__ Bt, long bZ,
    const float* __restrict__ bias, long biasZ,
    OUT_T* __restrict__ out, long outZ, long rs)
{
  constexpr int NT = K_CT / 64;
  __shared__ _Float16 ldsA[2 * 256 * 64];
  __shared__ _Float16 ldsB[2 * 256 * 64];

  const int z = blockIdx.z;
  A   += (size_t)z * aZ;
  Bt  += (size_t)z * bZ;
  if (BIAS) bias += (size_t)z * biasZ;
  out += (size_t)z * outZ;

  // T1: bijective XCD swizzle of (x,y); all grids here have nwg % 8 == 0.
  const int nwg = gridDim.x * gridDim.y;
  const int wg  = blockIdx.y * gridDim.x + blockIdx.x;
  const int sw  = (wg & 7) * (nwg >> 3) + (wg >> 3);
  const int bx  = sw % gridDim.x;
  const int by  = sw / gridDim.x;

  const int tid  = threadIdx.x;
  const int wave = tid >> 6;
  const int lane = tid & 63;
  const int q    = lane >> 4;
  const int l16  = lane & 15;
  const int l8   = lane >> 3;
  const int l7   = lane & 7;

  const int m0   = by * 256;
  const int n0   = bx * 256;
  const int wm   = wave >> 2;   // 0..1 -> 128-row slab of A-tile
  const int wn   = wave & 3;    // 0..3 -> 64-col slab of B-tile
  const int wrow = wm * 128;
  const int wcol = wn * 64;

  // Pre-swizzled global source + linear LDS dest; slot j of row r holds
  // k-chunk j^(r&7).
  const int swz_st = ((l7 ^ l8) << 3);
  const _Float16* paB = A  + (size_t)(m0 + wave * 16 + l8) * K_CT + swz_st;
  const _Float16* pbB = Bt + (size_t)(n0 + wave * 16 + l8) * K_CT + swz_st;

  int a_base[2], b_base[2];
#pragma unroll
  for (int kk = 0; kk < 2; ++kk) {
    int swr = (((kk * 4 + q) ^ (l16 & 7)) << 4);
    a_base[kk] = (wrow + l16) * 128 + swr;
    b_base[kk] = (wcol + l16) * 128 + swr;
  }

  f32x4 acc[8][4];
#pragma unroll
  for (int r = 0; r < 8; ++r)
#pragma unroll
    for (int c = 0; c < 4; ++c)
      acc[r][c] = (f32x4){0.f, 0.f, 0.f, 0.f};

  const char* lA = (const char*)ldsA;
  const char* lB = (const char*)ldsB;

#define STAGE_A(bufe, hh, ptr)                                                        \
  {                                                                                   \
    _Pragma("unroll")                                                                 \
    for (int i_ = 0; i_ < 2; ++i_)                                                    \
      async_cp16((ptr) + (size_t)((hh) * 128 + i_ * 8) * K_CT,                        \
                 (void*)(ldsA + (bufe) + (hh) * 8192 + (wave * 2 + i_) * 512));       \
  }
#define STAGE_B(bufe, hh, ptr)                                                        \
  {                                                                                   \
    _Pragma("unroll")                                                                 \
    for (int i_ = 0; i_ < 2; ++i_)                                                    \
      async_cp16((ptr) + (size_t)((hh) * 128 + i_ * 8) * K_CT,                        \
                 (void*)(ldsB + (bufe) + (hh) * 8192 + (wave * 2 + i_) * 512));       \
  }

  // Prologue: stage tile 0 fully, drain, publish, preload S0(0) registers.
  STAGE_A(0, 0, paB) STAGE_A(0, 1, paB)
  STAGE_B(0, 0, pbB) STAGE_B(0, 1, pbB)
  asm volatile("s_waitcnt vmcnt(0)" ::: "memory");
  __builtin_amdgcn_s_barrier();

  f16x8 afA[4], afB[4], bfv0[4], bfv1[4];
#pragma unroll
  for (int r = 0; r < 4; ++r) afA[r]  = *(const f16x8*)(lA + a_base[0] + r * 2048);
#pragma unroll
  for (int c = 0; c < 4; ++c) bfv0[c] = *(const f16x8*)(lB + b_base[0] + c * 2048);

  const _Float16* pa_t = paB + 64;   // -> tile t+1
  const _Float16* pb_t = pbB + 64;

  for (int t = 0; t < NT; ++t) {
    const int bofs  = (t & 1) * 32768;        // byte offset, current buffer
    const int nofs  = bofs ^ 32768;           // byte offset, next buffer
    const int nbufe = ((t + 1) & 1) * 16384;  // elem offset, next buffer

    // ---- P0: reads for S1; stage A(t+1); MFMA S0 ----
#pragma unroll
    for (int r = 0; r < 4; ++r) afB[r]  = *(const f16x8*)(lA + bofs + a_base[1] + r * 2048);
#pragma unroll
    for (int c = 0; c < 4; ++c) bfv1[c] = *(const f16x8*)(lB + bofs + b_base[1] + c * 2048);
    if (t + 1 < NT) { STAGE_A(nbufe, 0, pa_t) STAGE_A(nbufe, 1, pa_t) }
    __builtin_amdgcn_s_setprio(1);
#pragma unroll
    for (int c = 0; c < 4; ++c)
#pragma unroll
      for (int r = 0; r < 4; ++r)
        acc[r][c] = __builtin_amdgcn_mfma_f32_16x16x32_f16(afA[r], bfv0[c], acc[r][c], 0, 0, 0);
    __builtin_amdgcn_s_setprio(0);
    __builtin_amdgcn_s_barrier();

    // ---- P1: reads for S2; stage B(t+1); MFMA S1 ----
#pragma unroll
    for (int r = 0; r < 4; ++r) afA[r] = *(const f16x8*)(lA + bofs + a_base[0] + (4 + r) * 2048);
    if (t + 1 < NT) { STAGE_B(nbufe, 0, pb_t) STAGE_B(nbufe, 1, pb_t) }
    __builtin_amdgcn_s_setprio(1);
#pragma unroll
    for (int c = 0; c < 4; ++c)
#pragma unroll
      for (int r = 0; r < 4; ++r)
        acc[r][c] = __builtin_amdgcn_mfma_f32_16x16x32_f16(afB[r], bfv1[c], acc[r][c], 0, 0, 0);
    __builtin_amdgcn_s_setprio(0);
    __builtin_amdgcn_s_barrier();

    // ---- P2: reads for S3; MFMA S2; end-of-tile vmcnt + publish ----
#pragma unroll
    for (int r = 0; r < 4; ++r) afB[r] = *(const f16x8*)(lA + bofs + a_base[1] + (4 + r) * 2048);
    __builtin_amdgcn_s_setprio(1);
#pragma unroll
    for (int c = 0; c < 4; ++c)
#pragma unroll
      for (int r = 0; r < 4; ++r)
        acc[4 + r][c] = __builtin_amdgcn_mfma_f32_16x16x32_f16(afA[r], bfv0[c], acc[4 + r][c], 0, 0, 0);
    __builtin_amdgcn_s_setprio(0);
    // t+1 staged at P0/P1 (>=1.5 phases ago) -> this wait is ~free; the
    // following barrier publishes all waves' staged data.
    asm volatile("s_waitcnt vmcnt(0)" ::: "memory");
    __builtin_amdgcn_s_barrier();

    // ---- P3: reads for S0(t+1) from buf^1; MFMA S3 ----
    if (t + 1 < NT) {
#pragma unroll
      for (int r = 0; r < 4; ++r) afA[r]  = *(const f16x8*)(lA + nofs + a_base[0] + r * 2048);
#pragma unroll
      for (int c = 0; c < 4; ++c) bfv0[c] = *(const f16x8*)(lB + nofs + b_base[0] + c * 2048);
    }
    __builtin_amdgcn_s_setprio(1);
#pragma unroll
    for (int c = 0; c < 4; ++c)
#pragma unroll
      for (int r = 0; r < 4; ++r)
        acc[4 + r][c] = __builtin_amdgcn_mfma_f32_16x16x32_f16(afB[r], bfv1[c], acc[4 + r][c], 0, 0, 0);
    __builtin_amdgcn_s_setprio(0);
    __builtin_amdgcn_s_barrier();

    pa_t += 64;
    pb_t += 64;
  }
#undef STAGE_A
#undef STAGE_B

  // Epilogue: D[row=q*4+i][col=l16] per 16x16 frag (verified C/D layout).
#pragma unroll
  for (int c = 0; c < 4; ++c) {
    int col = n0 + wcol + c * 16 + l16;
    float bv = BIAS ? bias[col] : 0.f;
#pragma unroll
    for (int r = 0; r < 8; ++r) {
      int row = m0 + wrow + r * 16 + q * 4;
      f32x4 v = acc[r][c];
#pragma unroll
      for (int i = 0; i < 4; ++i) {
        float xv = v[i] + bv;
        if (RELU) xv = fmaxf(xv, 0.f);
        store_val(out + (size_t)(row + i) * rs + col, xv);
      }
    }
  }
}

// ---------------------------------------------------------------------------
__global__ void cast_f32_f16(const float* __restrict__ in, _Float16* __restrict__ out, int n) {
  int i = (blockIdx.x * blockDim.x + threadIdx.x) * 4;
  if (i >= n) return;
  float4 v = *(const float4*)(in + i);
  union { _Float16 h[4]; uint2 u; } r;
  r.h[0] = (_Float16)v.x; r.h[1] = (_Float16)v.y;
  r.h[2] = (_Float16)v.z; r.h[3] = (_Float16)v.w;
  *(uint2*)(out + i) = r.u;
}

// in [R][Cn] fp32 (batched over z) -> out [Cn][R] fp16
__global__ void transpose_cast(const float* __restrict__ in, _Float16* __restrict__ out,
                               int R, int Cn) {
  __shared__ float tile[32][33];
  in  += (size_t)blockIdx.z * R * Cn;
  out += (size_t)blockIdx.z * R * Cn;
  int c0 = blockIdx.x * 32, r0 = blockIdx.y * 32;
  int tx = threadIdx.x, ty = threadIdx.y;
#pragma unroll
  for (int i = ty; i < 32; i += 8)
    tile[i][tx] = in[(size_t)(r0 + i) * Cn + c0 + tx];
  __syncthreads();
#pragma unroll
  for (int i = ty; i < 32; i += 8)
    out[(size_t)(c0 + i) * R + r0 + tx] = (_Float16)tile[tx][i];
}

// scores = softmax(g[B][D](f16) @ w2[D][8] + b2); one wave per row,
// 4 rows per block, shuffle-only reduction.
__global__ void gate2_softmax(const _Float16* __restrict__ g, const float* __restrict__ w2,
                              const float* __restrict__ b2, float* __restrict__ scores) {
  int wv   = threadIdx.x >> 6;           // 0..3
  int lane = threadIdx.x & 63;
  int b    = blockIdx.x * 4 + wv;
  const _Float16* gr = g + (size_t)b * D_DIM;
  float acc[8];
#pragma unroll
  for (int e = 0; e < 8; ++e) acc[e] = 0.f;
#pragma unroll
  for (int half = 0; half < 2; ++half) {
    int d0 = lane * 8 + half * 512;
    f16x8 gv = *(const f16x8*)(gr + d0);
#pragma unroll
    for (int j = 0; j < 8; ++j) {
      float gx = (float)gv[j];
#pragma unroll
      for (int e = 0; e < 8; ++e) acc[e] += gx * w2[(d0 + j) * 8 + e];
    }
  }
#pragma unroll
  for (int s = 32; s > 0; s >>= 1)
#pragma unroll
    for (int e = 0; e < 8; ++e) acc[e] += __shfl_xor(acc[e], s);
  if (lane == 0) {
    float mx = acc[0] + b2[0];
    float v[8];
    v[0] = mx;
#pragma unroll
    for (int e = 1; e < 8; ++e) { v[e] = acc[e] + b2[e]; mx = fmaxf(mx, v[e]); }
    float ex[8], sum = 0.f;
#pragma unroll
    for (int e = 0; e < 8; ++e) { ex[e] = expf(v[e] - mx); sum += ex[e]; }
    float inv = 1.f / sum;
#pragma unroll
    for (int e = 0; e < 8; ++e) scores[(size_t)b * 8 + e] = ex[e] * inv;
  }
}

// bc[e][c] = cb[c] + sum_k b2[e][k] * cw[k][c]   (combined classifier bias)
__global__ void combined_bias(const float* __restrict__ b2, const float* __restrict__ cw,
                              const float* __restrict__ cb, float* __restrict__ bc) {
  int e  = blockIdx.y;
  int cl = threadIdx.x & 63;
  int c  = blockIdx.x * 64 + cl;
  int ks = threadIdx.x >> 6;  // 4 k-slices
  float acc = 0.f;
  for (int k = ks; k < H_DIM; k += 4)
    acc += b2[e * H_DIM + k] * cw[(size_t)k * C_DIM + c];
  __shared__ float red[256];
  red[threadIdx.x] = acc;
  __syncthreads();
  if (ks == 0)
    bc[(size_t)e * C_DIM + c] = red[cl] + red[cl + 64] + red[cl + 128] + red[cl + 192] + cb[c];
}

// ---------------------------------------------------------------------------
extern "C" void kernel_launch(void* const* d_in, const int* in_sizes, int n_in,
                              void* d_out, int out_size, void* d_ws, size_t ws_size,
                              hipStream_t stream) {
  const float* x   = (const float*)d_in[0];
  const float* gw1 = (const float*)d_in[1];
  const float* gb1 = (const float*)d_in[2];
  const float* gw2 = (const float*)d_in[3];
  const float* gb2 = (const float*)d_in[4];
  const float* W1  = (const float*)d_in[5];
  const float* b1  = (const float*)d_in[6];
  const float* W2  = (const float*)d_in[7];
  const float* b2  = (const float*)d_in[8];
  const float* cw  = (const float*)d_in[9];
  const float* cb  = (const float*)d_in[10];

  char* ws = (char*)d_ws;
  _Float16* xb     = (_Float16*)(ws);                    // B*D        16 MB
  _Float16* g      = (_Float16*)(ws + 16777216ull);      // B*D        16 MB
  _Float16* gw1t   = (_Float16*)(ws + 33554432ull);      // D*D         2 MB
  _Float16* W1t    = (_Float16*)(ws + 35651584ull);      // E*H*D      32 MB
  _Float16* W2c    = (_Float16*)(ws + 69206016ull);      // E*H*H      64 MB (cast, NOT transposed)
  _Float16* cwt    = (_Float16*)(ws + 136314880ull);     // C*H         4 MB
  _Float16* WcombT = (_Float16*)(ws + 140509184ull);     // E*C*H      32 MB
  float*    bc     = (float*)   (ws + 174063616ull);     // E*C        32 KB
  _Float16* h_all  = (_Float16*)(ws + 174096384ull);     // E*B*H     256 MB
                                                         // total ~422 MB

  float* logits = (float*)d_out;
  float* scores = logits + (size_t)B_DIM * E_DIM * C_DIM;

  // Precision prep: casts + [N][K] weight transposes
  cast_f32_f16<<<B_DIM * D_DIM / 4 / 256, 256, 0, stream>>>(x, xb, B_DIM * D_DIM);
  transpose_cast<<<dim3(32, 32, 1), dim3(32, 8), 0, stream>>>(gw1, gw1t, D_DIM, D_DIM);
  transpose_cast<<<dim3(64, 32, 8), dim3(32, 8), 0, stream>>>(W1, W1t, D_DIM, H_DIM);
  cast_f32_f16<<<E_DIM * H_DIM * H_DIM / 4 / 256, 256, 0, stream>>>(W2, W2c, E_DIM * H_DIM * H_DIM);
  transpose_cast<<<dim3(32, 64, 1), dim3(32, 8), 0, stream>>>(cw, cwt, H_DIM, C_DIM);

  // Router (128^2 kernel)
  gemm_bt<true, true, _Float16><<<dim3(8, 64, 1), 256, 0, stream>>>(
      xb, 0, gw1t, 0, gb1, 0, g, 0, D_DIM, (long)D_DIM);
  gate2_softmax<<<B_DIM / 4, 256, 0, stream>>>(g, gw2, gb2, scores);

  // Classifier folding: WcombT[e][c][h'] = sum_k2 Wc[k2][c] * W2[e][h'][k2]
  gemm256<false, false, _Float16, H_DIM><<<dim3(8, 4, 8), 512, 0, stream>>>(
      cwt, 0, W2c, (long)H_DIM * H_DIM, nullptr, 0,
      WcombT, (long)C_DIM * H_DIM, (long)H_DIM);
  combined_bias<<<dim3(C_DIM / 64, E_DIM), 256, 0, stream>>>(b2, cw, cb, bc);

  // Layer 1, all experts batched: h_all[e] = relu(x @ W1[e] + b1[e])
  gemm256<true, true, _Float16, D_DIM><<<dim3(8, 32, 8), 512, 0, stream>>>(
      xb, 0, W1t, (long)H_DIM * D_DIM, b1, (long)H_DIM,
      h_all, (long)B_DIM * H_DIM, (long)H_DIM);

  // Fused layer2+classifier: logits[:,e,:] = h_all[e] @ Wcomb[e] + bc[e]
  gemm256<false, true, float, H_DIM><<<dim3(4, 32, 8), 512, 0, stream>>>(
      h_all, (long)B_DIM * H_DIM, WcombT, (long)C_DIM * H_DIM, bc, (long)C_DIM,
      logits, (long)C_DIM, (long)(E_DIM * C_DIM));
}

// Round 6
// 1427.145 us; speedup vs baseline: 1.1427x; 1.0113x over previous
//
#include <hip/hip_runtime.h>
#include <stdint.h>

#define B_DIM 8192
#define D_DIM 1024
#define H_DIM 2048
#define E_DIM 8
#define C_DIM 1024

typedef _Float16 f16x8 __attribute__((ext_vector_type(8)));
typedef float f32x4 __attribute__((ext_vector_type(4)));

__device__ __forceinline__ void store_val(float* p, float v) { *p = v; }
__device__ __forceinline__ void store_val(_Float16* p, float v) { *p = (_Float16)v; }

__device__ __forceinline__ void async_cp16(const void* g, void* l) {
  __builtin_amdgcn_global_load_lds((const __attribute__((address_space(1))) void*)g,
                                   (__attribute__((address_space(3))) void*)l, 16, 0, 0);
}

// ---------------------------------------------------------------------------
// 128x128 tile kernel (m97 structure, 32 KiB LDS -> ~5 blocks/CU).
// Used for router + classifier-fold GEMMs.
// ---------------------------------------------------------------------------
template <bool RELU, bool BIAS, typename OUT_T>
__global__ void __launch_bounds__(256) gemm_bt(
    const _Float16* __restrict__ A, long aZ,
    const _Float16* __restrict__ Bt, long bZ,
    const float* __restrict__ bias, long biasZ,
    OUT_T* __restrict__ out, long outZ,
    int K, long rs)
{
  __shared__ _Float16 ldsA[128 * 64];
  __shared__ _Float16 ldsB[128 * 64];

  const int z = blockIdx.z;
  A   += (size_t)z * aZ;
  Bt  += (size_t)z * bZ;
  if (BIAS) bias += (size_t)z * biasZ;
  out += (size_t)z * outZ;

  const int tid  = threadIdx.x;
  const int wave = tid >> 6;
  const int lane = tid & 63;
  const int q    = lane >> 4;
  const int l16  = lane & 15;
  const int l8   = lane >> 3;
  const int l7   = lane & 7;

  const int m0   = blockIdx.y * 128;
  const int n0   = blockIdx.x * 128;
  const int wrow = (wave >> 1) * 64;
  const int wcol = (wave & 1) * 64;

  const int swz_st = ((l7 ^ l8) << 3);
  const _Float16* pa[4];
  const _Float16* pb[4];
#pragma unroll
  for (int i = 0; i < 4; ++i) {
    int ci = wave * 4 + i;
    pa[i] = A  + (size_t)(m0 + ci * 8 + l8) * K + swz_st;
    pb[i] = Bt + (size_t)(n0 + ci * 8 + l8) * K + swz_st;
  }

  int a_off[2][4], b_off[2][4];
#pragma unroll
  for (int kk = 0; kk < 2; ++kk) {
#pragma unroll
    for (int r = 0; r < 4; ++r) {
      int sw = ((kk * 4 + q) ^ (l16 & 7)) << 4;
      a_off[kk][r] = (wrow + r * 16 + l16) * 128 + sw;
      b_off[kk][r] = (wcol + r * 16 + l16) * 128 + sw;
    }
  }

  f32x4 acc[4][4];
#pragma unroll
  for (int r = 0; r < 4; ++r)
#pragma unroll
    for (int c = 0; c < 4; ++c)
      acc[r][c] = (f32x4){0.f, 0.f, 0.f, 0.f};

  const char* lAc = (const char*)ldsA;
  const char* lBc = (const char*)ldsB;

  for (int kt = 0; kt < K; kt += 64) {
    __syncthreads();
#pragma unroll
    for (int i = 0; i < 4; ++i) {
      int ci = wave * 4 + i;
      async_cp16(pa[i], ldsA + ci * 512);
      async_cp16(pb[i], ldsB + ci * 512);
      pa[i] += 64;
      pb[i] += 64;
    }
    __syncthreads();
#pragma unroll
    for (int kk = 0; kk < 2; ++kk) {
      f16x8 af[4], bfv[4];
#pragma unroll
      for (int r = 0; r < 4; ++r) af[r]  = *(const f16x8*)(lAc + a_off[kk][r]);
#pragma unroll
      for (int c = 0; c < 4; ++c) bfv[c] = *(const f16x8*)(lBc + b_off[kk][c]);
#pragma unroll
      for (int r = 0; r < 4; ++r)
#pragma unroll
        for (int c = 0; c < 4; ++c)
          acc[r][c] = __builtin_amdgcn_mfma_f32_16x16x32_f16(af[r], bfv[c], acc[r][c], 0, 0, 0);
    }
  }

#pragma unroll
  for (int c = 0; c < 4; ++c) {
    int col = n0 + wcol + c * 16 + l16;
    float bv = BIAS ? bias[col] : 0.f;
#pragma unroll
    for (int r = 0; r < 4; ++r) {
      int row = m0 + wrow + r * 16 + q * 4;
      f32x4 v = acc[r][c];
#pragma unroll
      for (int i = 0; i < 4; ++i) {
        float xv = v[i] + bv;
        if (RELU) xv = fmaxf(xv, 0.f);
        store_val(out + (size_t)(row + i) * rs + col, xv);
      }
    }
  }
}

// ---------------------------------------------------------------------------
// 256x256 tile, BK=32, 8 waves (2Mx4N), double-buffered LDS = 64 KiB total
// -> TWO co-resident blocks per CU (16 waves). The sibling block's MFMA burst
// covers this block's LDS-read/stage/vmcnt regions (m97/m114 mechanism) —
// replaces all failed intra-block pipelining attempts (R1-R5, all ~31%).
// Per K-tile (k=32): 2 phases.
//   ph0: ds_read A rows0-3 + B cols0-3 (8 b128); stage tile t+1 (2A+2B
//        gload_lds) into buf^1; 16 MFMA (rows0-3); barrier
//   ph1: ds_read A rows4-7 (4 b128); 16 MFMA (rows4-7); vmcnt(0); barrier
// Stage safety: A(t+1)->buf^1 at ph0(t): buf^1 A last read ph1(t-1), those
// reads complete before that wave's ph1 MFMAs -> before barrier(t-1,ph1),
// which all waves crossed before any ph0(t) stage. B: last read ph0(t-1),
// two barriers back. vmcnt(0) at ph1 drains stages issued ~1 phase earlier;
// residual stall is covered by the co-resident block.
// LDS rows are 64 B; swizzle: physical chunk = logical_chunk ^ ((row>>1)&3)
// -> per quarter-wave all 8 granule-groups x2 lanes (conflict-free).
// Staging stays dest-linear: source chunk offset ((l&3)^((l>>3)&3))*8.
// ---------------------------------------------------------------------------
template <bool RELU, bool BIAS, typename OUT_T, int K_CT>
__global__ void __launch_bounds__(512) gemm256(
    const _Float16* __restrict__ A, long aZ,
    const _Float16* __restrict__ Bt, long bZ,
    const float* __restrict__ bias, long biasZ,
    OUT_T* __restrict__ out, long outZ, long rs)
{
  constexpr int NT = K_CT / 32;
  __shared__ _Float16 ldsA[2 * 256 * 32];  // 32 KiB
  __shared__ _Float16 ldsB[2 * 256 * 32];  // 32 KiB

  const int z = blockIdx.z;
  A   += (size_t)z * aZ;
  Bt  += (size_t)z * bZ;
  if (BIAS) bias += (size_t)z * biasZ;
  out += (size_t)z * outZ;

  // T1: bijective XCD swizzle of (x,y); all grids here have nwg % 8 == 0.
  const int nwg = gridDim.x * gridDim.y;
  const int wg  = blockIdx.y * gridDim.x + blockIdx.x;
  const int sw  = (wg & 7) * (nwg >> 3) + (wg >> 3);
  const int bx  = sw % gridDim.x;
  const int by  = sw / gridDim.x;

  const int tid  = threadIdx.x;
  const int wave = tid >> 6;
  const int lane = tid & 63;
  const int q    = lane >> 4;
  const int l16  = lane & 15;

  const int m0   = by * 256;
  const int n0   = bx * 256;
  const int wm   = wave >> 2;   // 0..1 -> 128-row slab of A-tile
  const int wn   = wave & 3;    // 0..3 -> 64-col slab of B-tile
  const int wrow = wm * 128;
  const int wcol = wn * 64;

  // Staging: per wave 2 A-instrs + 2 B-instrs per tile; instr i covers 16
  // rows starting at (wave*2+i)*16; lane l -> row +(l>>2), chunk (l&3),
  // pre-swizzled global source chunk = (l&3) ^ ((l>>3)&3).
  const int sw8 = (((lane & 3) ^ ((lane >> 3) & 3)) << 3);
  const _Float16* pa[2];
  const _Float16* pb[2];
#pragma unroll
  for (int i = 0; i < 2; ++i) {
    int r0 = (wave * 2 + i) * 16;
    pa[i] = A  + (size_t)(m0 + r0 + (lane >> 2)) * K_CT + sw8;
    pb[i] = Bt + (size_t)(n0 + r0 + (lane >> 2)) * K_CT + sw8;
  }

  // ds_read byte offsets: row*64 + ((q ^ ((row>>1)&3))<<4)
  int a_off[8], b_off[4];
#pragma unroll
  for (int r = 0; r < 8; ++r) {
    int row = wrow + r * 16 + l16;
    a_off[r] = row * 64 + ((q ^ ((row >> 1) & 3)) << 4);
  }
#pragma unroll
  for (int c = 0; c < 4; ++c) {
    int row = wcol + c * 16 + l16;
    b_off[c] = row * 64 + ((q ^ ((row >> 1) & 3)) << 4);
  }

  f32x4 acc[8][4];
#pragma unroll
  for (int r = 0; r < 8; ++r)
#pragma unroll
    for (int c = 0; c < 4; ++c)
      acc[r][c] = (f32x4){0.f, 0.f, 0.f, 0.f};

  const char* lA = (const char*)ldsA;
  const char* lB = (const char*)ldsB;

  // Prologue: stage tile 0 into buf 0, drain, publish.
#pragma unroll
  for (int i = 0; i < 2; ++i) {
    int ci = wave * 2 + i;
    async_cp16(pa[i], ldsA + ci * 512);
    async_cp16(pb[i], ldsB + ci * 512);
    pa[i] += 32;  // -> tile 1
    pb[i] += 32;
  }
  asm volatile("s_waitcnt vmcnt(0)" ::: "memory");
  __builtin_amdgcn_s_barrier();

  for (int t = 0; t < NT; ++t) {
    const int bofs  = (t & 1) * 16384;        // byte offset, current buffer
    const int nbufe = ((t + 1) & 1) * 8192;   // elem offset, next buffer

    // ---- ph0: reads rows0-3 + B; stage tile t+1; MFMA rows0-3 ----
    f16x8 af[4], bf[4];
#pragma unroll
    for (int r = 0; r < 4; ++r) af[r] = *(const f16x8*)(lA + bofs + a_off[r]);
#pragma unroll
    for (int c = 0; c < 4; ++c) bf[c] = *(const f16x8*)(lB + bofs + b_off[c]);
    if (t + 1 < NT) {
#pragma unroll
      for (int i = 0; i < 2; ++i) {
        int ci = wave * 2 + i;
        async_cp16(pa[i], ldsA + nbufe + ci * 512);
        async_cp16(pb[i], ldsB + nbufe + ci * 512);
      }
    }
    __builtin_amdgcn_s_setprio(1);
#pragma unroll
    for (int c = 0; c < 4; ++c)
#pragma unroll
      for (int r = 0; r < 4; ++r)
        acc[r][c] = __builtin_amdgcn_mfma_f32_16x16x32_f16(af[r], bf[c], acc[r][c], 0, 0, 0);
    __builtin_amdgcn_s_setprio(0);
    __builtin_amdgcn_s_barrier();

    // ---- ph1: reads rows4-7; MFMA rows4-7; drain stages; publish ----
    f16x8 af2[4];
#pragma unroll
    for (int r = 0; r < 4; ++r) af2[r] = *(const f16x8*)(lA + bofs + a_off[4 + r]);
    __builtin_amdgcn_s_setprio(1);
#pragma unroll
    for (int c = 0; c < 4; ++c)
#pragma unroll
      for (int r = 0; r < 4; ++r)
        acc[4 + r][c] = __builtin_amdgcn_mfma_f32_16x16x32_f16(af2[r], bf[c], acc[4 + r][c], 0, 0, 0);
    __builtin_amdgcn_s_setprio(0);
    asm volatile("s_waitcnt vmcnt(0)" ::: "memory");
    __builtin_amdgcn_s_barrier();

#pragma unroll
    for (int i = 0; i < 2; ++i) { pa[i] += 32; pb[i] += 32; }
  }

  // Epilogue: D[row=q*4+i][col=l16] per 16x16 frag (verified C/D layout).
#pragma unroll
  for (int c = 0; c < 4; ++c) {
    int col = n0 + wcol + c * 16 + l16;
    float bv = BIAS ? bias[col] : 0.f;
#pragma unroll
    for (int r = 0; r < 8; ++r) {
      int row = m0 + wrow + r * 16 + q * 4;
      f32x4 v = acc[r][c];
#pragma unroll
      for (int i = 0; i < 4; ++i) {
        float xv = v[i] + bv;
        if (RELU) xv = fmaxf(xv, 0.f);
        store_val(out + (size_t)(row + i) * rs + col, xv);
      }
    }
  }
}

// ---------------------------------------------------------------------------
__global__ void cast_f32_f16(const float* __restrict__ in, _Float16* __restrict__ out, int n) {
  int i = (blockIdx.x * blockDim.x + threadIdx.x) * 4;
  if (i >= n) return;
  float4 v = *(const float4*)(in + i);
  union { _Float16 h[4]; uint2 u; } r;
  r.h[0] = (_Float16)v.x; r.h[1] = (_Float16)v.y;
  r.h[2] = (_Float16)v.z; r.h[3] = (_Float16)v.w;
  *(uint2*)(out + i) = r.u;
}

// in [R][Cn] fp32 (batched over z) -> out [Cn][R] fp16
__global__ void transpose_cast(const float* __restrict__ in, _Float16* __restrict__ out,
                               int R, int Cn) {
  __shared__ float tile[32][33];
  in  += (size_t)blockIdx.z * R * Cn;
  out += (size_t)blockIdx.z * R * Cn;
  int c0 = blockIdx.x * 32, r0 = blockIdx.y * 32;
  int tx = threadIdx.x, ty = threadIdx.y;
#pragma unroll
  for (int i = ty; i < 32; i += 8)
    tile[i][tx] = in[(size_t)(r0 + i) * Cn + c0 + tx];
  __syncthreads();
#pragma unroll
  for (int i = ty; i < 32; i += 8)
    out[(size_t)(c0 + i) * R + r0 + tx] = (_Float16)tile[tx][i];
}

// scores = softmax(g[B][D](f16) @ w2[D][8] + b2); one wave per row,
// 4 rows per block, shuffle-only reduction.
__global__ void gate2_softmax(const _Float16* __restrict__ g, const float* __restrict__ w2,
                              const float* __restrict__ b2, float* __restrict__ scores) {
  int wv   = threadIdx.x >> 6;           // 0..3
  int lane = threadIdx.x & 63;
  int b    = blockIdx.x * 4 + wv;
  const _Float16* gr = g + (size_t)b * D_DIM;
  float acc[8];
#pragma unroll
  for (int e = 0; e < 8; ++e) acc[e] = 0.f;
#pragma unroll
  for (int half = 0; half < 2; ++half) {
    int d0 = lane * 8 + half * 512;
    f16x8 gv = *(const f16x8*)(gr + d0);
#pragma unroll
    for (int j = 0; j < 8; ++j) {
      float gx = (float)gv[j];
#pragma unroll
      for (int e = 0; e < 8; ++e) acc[e] += gx * w2[(d0 + j) * 8 + e];
    }
  }
#pragma unroll
  for (int s = 32; s > 0; s >>= 1)
#pragma unroll
    for (int e = 0; e < 8; ++e) acc[e] += __shfl_xor(acc[e], s);
  if (lane == 0) {
    float mx = acc[0] + b2[0];
    float v[8];
    v[0] = mx;
#pragma unroll
    for (int e = 1; e < 8; ++e) { v[e] = acc[e] + b2[e]; mx = fmaxf(mx, v[e]); }
    float ex[8], sum = 0.f;
#pragma unroll
    for (int e = 0; e < 8; ++e) { ex[e] = expf(v[e] - mx); sum += ex[e]; }
    float inv = 1.f / sum;
#pragma unroll
    for (int e = 0; e < 8; ++e) scores[(size_t)b * 8 + e] = ex[e] * inv;
  }
}

// bc[e][c] = cb[c] + sum_k b2[e][k] * cw[k][c]   (combined classifier bias)
__global__ void combined_bias(const float* __restrict__ b2, const float* __restrict__ cw,
                              const float* __restrict__ cb, float* __restrict__ bc) {
  int e  = blockIdx.y;
  int cl = threadIdx.x & 63;
  int c  = blockIdx.x * 64 + cl;
  int ks = threadIdx.x >> 6;  // 4 k-slices
  float acc = 0.f;
  for (int k = ks; k < H_DIM; k += 4)
    acc += b2[e * H_DIM + k] * cw[(size_t)k * C_DIM + c];
  __shared__ float red[256];
  red[threadIdx.x] = acc;
  __syncthreads();
  if (ks == 0)
    bc[(size_t)e * C_DIM + c] = red[cl] + red[cl + 64] + red[cl + 128] + red[cl + 192] + cb[c];
}

// ---------------------------------------------------------------------------
extern "C" void kernel_launch(void* const* d_in, const int* in_sizes, int n_in,
                              void* d_out, int out_size, void* d_ws, size_t ws_size,
                              hipStream_t stream) {
  const float* x   = (const float*)d_in[0];
  const float* gw1 = (const float*)d_in[1];
  const float* gb1 = (const float*)d_in[2];
  const float* gw2 = (const float*)d_in[3];
  const float* gb2 = (const float*)d_in[4];
  const float* W1  = (const float*)d_in[5];
  const float* b1  = (const float*)d_in[6];
  const float* W2  = (const float*)d_in[7];
  const float* b2  = (const float*)d_in[8];
  const float* cw  = (const float*)d_in[9];
  const float* cb  = (const float*)d_in[10];

  char* ws = (char*)d_ws;
  _Float16* xb     = (_Float16*)(ws);                    // B*D        16 MB
  _Float16* g      = (_Float16*)(ws + 16777216ull);      // B*D        16 MB
  _Float16* gw1t   = (_Float16*)(ws + 33554432ull);      // D*D         2 MB
  _Float16* W1t    = (_Float16*)(ws + 35651584ull);      // E*H*D      32 MB
  _Float16* W2c    = (_Float16*)(ws + 69206016ull);      // E*H*H      64 MB (cast, NOT transposed)
  _Float16* cwt    = (_Float16*)(ws + 136314880ull);     // C*H         4 MB
  _Float16* WcombT = (_Float16*)(ws + 140509184ull);     // E*C*H      32 MB
  float*    bc     = (float*)   (ws + 174063616ull);     // E*C        32 KB
  _Float16* h_all  = (_Float16*)(ws + 174096384ull);     // E*B*H     256 MB
                                                         // total ~422 MB

  float* logits = (float*)d_out;
  float* scores = logits + (size_t)B_DIM * E_DIM * C_DIM;

  // Precision prep: casts + [N][K] weight transposes
  cast_f32_f16<<<B_DIM * D_DIM / 4 / 256, 256, 0, stream>>>(x, xb, B_DIM * D_DIM);
  transpose_cast<<<dim3(32, 32, 1), dim3(32, 8), 0, stream>>>(gw1, gw1t, D_DIM, D_DIM);
  transpose_cast<<<dim3(64, 32, 8), dim3(32, 8), 0, stream>>>(W1, W1t, D_DIM, H_DIM);
  cast_f32_f16<<<E_DIM * H_DIM * H_DIM / 4 / 256, 256, 0, stream>>>(W2, W2c, E_DIM * H_DIM * H_DIM);
  transpose_cast<<<dim3(32, 64, 1), dim3(32, 8), 0, stream>>>(cw, cwt, H_DIM, C_DIM);

  // Router (128^2 kernel)
  gemm_bt<true, true, _Float16><<<dim3(8, 64, 1), 256, 0, stream>>>(
      xb, 0, gw1t, 0, gb1, 0, g, 0, D_DIM, (long)D_DIM);
  gate2_softmax<<<B_DIM / 4, 256, 0, stream>>>(g, gw2, gb2, scores);

  // Classifier folding: WcombT[e][c][h'] = sum_k2 Wc[k2][c] * W2[e][h'][k2]
  //   M=C=1024, N=H=2048, K=H=2048 -> gemm_bt grid (16,8,8) = 1024 blocks.
  gemm_bt<false, false, _Float16><<<dim3(16, 8, 8), 256, 0, stream>>>(
      cwt, 0, W2c, (long)H_DIM * H_DIM, nullptr, 0,
      WcombT, (long)C_DIM * H_DIM, H_DIM, (long)H_DIM);
  combined_bias<<<dim3(C_DIM / 64, E_DIM), 256, 0, stream>>>(b2, cw, cb, bc);

  // Layer 1, all experts batched: h_all[e] = relu(x @ W1[e] + b1[e])
  gemm256<true, true, _Float16, D_DIM><<<dim3(8, 32, 8), 512, 0, stream>>>(
      xb, 0, W1t, (long)H_DIM * D_DIM, b1, (long)H_DIM,
      h_all, (long)B_DIM * H_DIM, (long)H_DIM);

  // Fused layer2+classifier: logits[:,e,:] = h_all[e] @ Wcomb[e] + bc[e]
  gemm256<false, true, float, H_DIM><<<dim3(4, 32, 8), 512, 0, stream>>>(
      h_all, (long)B_DIM * H_DIM, WcombT, (long)C_DIM * H_DIM, bc, (long)C_DIM,
      logits, (long)C_DIM, (long)(E_DIM * C_DIM));
}